// Round 1
// baseline (182.778 us; speedup 1.0000x reference)
//
#include <hip/hip_runtime.h>
#include <math.h>

#define S 1024
#define C 128

__device__ __forceinline__ float wred_sum(float v) {
  #pragma unroll
  for (int off = 32; off; off >>= 1) v += __shfl_xor(v, off);
  return v;
}

// ---------------- GroupNorm: x[B,C,S] -> xn[B,C,S] (same layout) ----------------
// one block per (b, group); group = 4 channels x 1024 spatial = 4096 elems
__global__ __launch_bounds__(256) void gn_kernel(const float* __restrict__ x,
                                                 const float* __restrict__ w,
                                                 const float* __restrict__ bias,
                                                 float* __restrict__ xn) {
  const int b = blockIdx.x >> 5, g = blockIdx.x & 31;
  const float* xp = x + (size_t)(b * C + g * 4) * S;
  float* xnp = xn + (size_t)(b * C + g * 4) * S;
  float4 vals[4];
  float s = 0.f, ss = 0.f;
  #pragma unroll
  for (int i = 0; i < 4; ++i) {
    float4 v = ((const float4*)xp)[threadIdx.x + i * 256];
    vals[i] = v;
    s += (v.x + v.y) + (v.z + v.w);
    ss += v.x * v.x; ss += v.y * v.y; ss += v.z * v.z; ss += v.w * v.w;
  }
  s = wred_sum(s); ss = wred_sum(ss);
  __shared__ float red[8];
  const int lane = threadIdx.x & 63, wid = threadIdx.x >> 6;
  if (lane == 0) { red[wid] = s; red[4 + wid] = ss; }
  __syncthreads();
  float ts = (red[0] + red[1]) + (red[2] + red[3]);
  float tss = (red[4] + red[5]) + (red[6] + red[7]);
  float mean = ts * (1.f / 4096.f);
  float var = tss * (1.f / 4096.f) - mean * mean;
  float rstd = rsqrtf(var + 1e-5f);
  #pragma unroll
  for (int i = 0; i < 4; ++i) {
    float sc = w[g * 4 + i] * rstd;
    float sh = fmaf(-mean, sc, bias[g * 4 + i]);
    float4 v = vals[i];
    float4 o = make_float4(fmaf(v.x, sc, sh), fmaf(v.y, sc, sh),
                           fmaf(v.z, sc, sh), fmaf(v.w, sc, sh));
    ((float4*)xnp)[threadIdx.x + i * 256] = o;
  }
}

// ---------------- transpose 4 weight mats into WT[k][512] = [Wq^T|Wk^T|Wv^T|Wo^T] ----------------
__global__ __launch_bounds__(256) void wtrans_kernel(const float* __restrict__ Wq,
                                                     const float* __restrict__ Wk,
                                                     const float* __restrict__ Wv,
                                                     const float* __restrict__ Wo,
                                                     float* __restrict__ WT) {
  int idx = blockIdx.x * 256 + threadIdx.x;   // 65536 total
  int mat = idx >> 14, n = (idx >> 7) & 127, k = idx & 127;
  const float* W = mat == 0 ? Wq : (mat == 1 ? Wk : (mat == 2 ? Wv : Wo));
  WT[k * 512 + mat * 128 + n] = W[n * 128 + k];
}

// ---------------- QKV GEMM: out[n][m] = sum_k xn[b][k][m0+m] * W[n][k] + bias[n] ----------------
// A is K-major ([C][S] per batch). 64x64 tile, 256 threads, 4x4 microtile.
__global__ __launch_bounds__(256) void gemm_qkv(const float* __restrict__ xn,
                                                const float* __restrict__ WT,
                                                const float* __restrict__ bq,
                                                const float* __restrict__ bk,
                                                const float* __restrict__ bv,
                                                float* __restrict__ qkv) {
  const int m0 = blockIdx.x * 64;
  const int nt = blockIdx.y;          // 0..5
  const int b = blockIdx.z;
  const int mat = nt >> 1, nloc = (nt & 1) * 64;
  const int col0 = mat * 128 + nloc;
  const float* biasp = (mat == 0 ? bq : (mat == 1 ? bk : bv)) + nloc;
  const float* Ab = xn + (size_t)b * C * S + m0;
  float* outp = qkv + ((size_t)mat * 2 + b) * (C * S) + (size_t)nloc * S + m0;

  __shared__ float As[32][64];
  __shared__ float Bs[32][64];
  const int tx = threadIdx.x & 15, ty = threadIdx.x >> 4;
  float acc[4][4] = {};

  for (int kt = 0; kt < 4; ++kt) {
    const int k0 = kt * 32;
    __syncthreads();
    #pragma unroll
    for (int i = threadIdx.x; i < 2048; i += 256) {
      int kk = i >> 6, mm = i & 63;
      As[kk][mm] = Ab[(size_t)(k0 + kk) * S + mm];
      Bs[kk][mm] = WT[(k0 + kk) * 512 + col0 + mm];
    }
    __syncthreads();
    #pragma unroll
    for (int kk = 0; kk < 32; ++kk) {
      float4 a4 = *(const float4*)&As[kk][tx * 4];
      float4 b4 = *(const float4*)&Bs[kk][ty * 4];
      float av[4] = {a4.x, a4.y, a4.z, a4.w};
      float bv4[4] = {b4.x, b4.y, b4.z, b4.w};
      #pragma unroll
      for (int j = 0; j < 4; ++j)
        #pragma unroll
        for (int i = 0; i < 4; ++i)
          acc[j][i] = fmaf(bv4[j], av[i], acc[j][i]);
    }
  }
  #pragma unroll
  for (int j = 0; j < 4; ++j) {
    float bj = biasp[ty * 4 + j];
    float4 o = make_float4(acc[j][0] + bj, acc[j][1] + bj, acc[j][2] + bj, acc[j][3] + bj);
    *(float4*)&outp[(size_t)(ty * 4 + j) * S + tx * 4] = o;
  }
}

// ---------------- Attention: per (b,h): softmax(q_i * k[:]) @ v ----------------
// grid (4, 128, 2): 256 queries per block, 1 per thread; k,v staged in LDS.
__global__ __launch_bounds__(256) void attn_kernel(const float* __restrict__ qkv,
                                                   float* __restrict__ attnb) {
  const int h = blockIdx.y, b = blockIdx.z;
  const size_t base = ((size_t)b * C + h) * S;
  const float* qp = qkv + base;
  const float* kp = qkv + 2 * C * S + base;
  const float* vp = qkv + 4 * C * S + base;
  __shared__ float kl[S];
  __shared__ float vl[S];
  __shared__ float red[8];
  float4 k4 = ((const float4*)kp)[threadIdx.x];
  float4 v4 = ((const float4*)vp)[threadIdx.x];
  ((float4*)kl)[threadIdx.x] = k4;
  ((float4*)vl)[threadIdx.x] = v4;
  float kmax = fmaxf(fmaxf(k4.x, k4.y), fmaxf(k4.z, k4.w));
  float kmin = fminf(fminf(k4.x, k4.y), fminf(k4.z, k4.w));
  #pragma unroll
  for (int off = 32; off; off >>= 1) {
    kmax = fmaxf(kmax, __shfl_xor(kmax, off));
    kmin = fminf(kmin, __shfl_xor(kmin, off));
  }
  const int lane = threadIdx.x & 63, wid = threadIdx.x >> 6;
  if (lane == 0) { red[wid] = kmax; red[4 + wid] = kmin; }
  __syncthreads();
  kmax = fmaxf(fmaxf(red[0], red[1]), fmaxf(red[2], red[3]));
  kmin = fminf(fminf(red[4], red[5]), fminf(red[6], red[7]));

  const int qi = blockIdx.x * 256 + threadIdx.x;
  const float LOG2E = 1.4426950408889634f;
  float qs = qp[qi] * LOG2E;                 // scale=1 (HEAD_DIM=1)
  float mb = fmaxf(qs * kmax, qs * kmin);    // exact max of qs*k_j (log2 domain)
  float den0 = 0.f, den1 = 0.f, num0 = 0.f, num1 = 0.f;
  for (int j4 = 0; j4 < S / 4; ++j4) {
    float4 kk = ((const float4*)kl)[j4];     // broadcast read
    float4 vv = ((const float4*)vl)[j4];
    float e0 = exp2f(fmaf(qs, kk.x, -mb));
    float e1 = exp2f(fmaf(qs, kk.y, -mb));
    float e2 = exp2f(fmaf(qs, kk.z, -mb));
    float e3 = exp2f(fmaf(qs, kk.w, -mb));
    den0 += e0; num0 = fmaf(e0, vv.x, num0);
    den1 += e1; num1 = fmaf(e1, vv.y, num1);
    den0 += e2; num0 = fmaf(e2, vv.z, num0);
    den1 += e3; num1 = fmaf(e3, vv.w, num1);
  }
  attnb[base + qi] = (num0 + num1) / (den0 + den1);
}

// ---------------- Out proj + bias + residual: out[b][n][m] ----------------
__global__ __launch_bounds__(256) void gemm_out(const float* __restrict__ attnb,
                                                const float* __restrict__ WT,
                                                const float* __restrict__ bo,
                                                const float* __restrict__ x,
                                                float* __restrict__ out) {
  const int m0 = blockIdx.x * 64;
  const int nt = blockIdx.y;   // 0..1
  const int b = blockIdx.z;
  const int nloc = nt * 64;
  const int col0 = 384 + nloc;
  const float* Ab = attnb + (size_t)b * C * S + m0;
  const float* biasp = bo + nloc;
  const float* resp = x + (size_t)b * C * S + (size_t)nloc * S + m0;
  float* outp = out + (size_t)b * C * S + (size_t)nloc * S + m0;

  __shared__ float As[32][64];
  __shared__ float Bs[32][64];
  const int tx = threadIdx.x & 15, ty = threadIdx.x >> 4;
  float acc[4][4] = {};

  for (int kt = 0; kt < 4; ++kt) {
    const int k0 = kt * 32;
    __syncthreads();
    #pragma unroll
    for (int i = threadIdx.x; i < 2048; i += 256) {
      int kk = i >> 6, mm = i & 63;
      As[kk][mm] = Ab[(size_t)(k0 + kk) * S + mm];
      Bs[kk][mm] = WT[(k0 + kk) * 512 + col0 + mm];
    }
    __syncthreads();
    #pragma unroll
    for (int kk = 0; kk < 32; ++kk) {
      float4 a4 = *(const float4*)&As[kk][tx * 4];
      float4 b4 = *(const float4*)&Bs[kk][ty * 4];
      float av[4] = {a4.x, a4.y, a4.z, a4.w};
      float bv4[4] = {b4.x, b4.y, b4.z, b4.w};
      #pragma unroll
      for (int j = 0; j < 4; ++j)
        #pragma unroll
        for (int i = 0; i < 4; ++i)
          acc[j][i] = fmaf(bv4[j], av[i], acc[j][i]);
    }
  }
  #pragma unroll
  for (int j = 0; j < 4; ++j) {
    float bj = biasp[ty * 4 + j];
    const float* rrow = resp + (size_t)(ty * 4 + j) * S + tx * 4;
    float4 r = *(const float4*)rrow;
    float4 o = make_float4(acc[j][0] + bj + r.x, acc[j][1] + bj + r.y,
                           acc[j][2] + bj + r.z, acc[j][3] + bj + r.w);
    *(float4*)&outp[(size_t)(ty * 4 + j) * S + tx * 4] = o;
  }
}

extern "C" void kernel_launch(void* const* d_in, const int* in_sizes, int n_in,
                              void* d_out, int out_size, void* d_ws, size_t ws_size,
                              hipStream_t stream) {
  const float* x  = (const float*)d_in[0];
  const float* gw = (const float*)d_in[1];
  const float* gb = (const float*)d_in[2];
  const float* Wq = (const float*)d_in[3];
  const float* bq = (const float*)d_in[4];
  const float* Wk = (const float*)d_in[5];
  const float* bk = (const float*)d_in[6];
  const float* Wv = (const float*)d_in[7];
  const float* bv = (const float*)d_in[8];
  const float* Wo = (const float*)d_in[9];
  const float* bo = (const float*)d_in[10];
  float* out = (float*)d_out;

  float* ws = (float*)d_ws;
  float* xn  = ws;                       // 262144 floats (reused as attention output)
  float* qkv = ws + 262144;              // 786432 floats, layout [mat][b][C][S]
  float* WT  = ws + 262144 + 786432;     // 65536 floats: [k][512]

  hipLaunchKernelGGL(wtrans_kernel, dim3(256), dim3(256), 0, stream, Wq, Wk, Wv, Wo, WT);
  hipLaunchKernelGGL(gn_kernel, dim3(64), dim3(256), 0, stream, x, gw, gb, xn);
  hipLaunchKernelGGL(gemm_qkv, dim3(16, 6, 2), dim3(256), 0, stream, xn, WT, bq, bk, bv, qkv);
  hipLaunchKernelGGL(attn_kernel, dim3(4, 128, 2), dim3(256), 0, stream, qkv, xn);
  hipLaunchKernelGGL(gemm_out, dim3(16, 2, 2), dim3(256), 0, stream, xn, WT, bo, x, out);
}

// Round 3
// 140.158 us; speedup vs baseline: 1.3041x; 1.3041x over previous
//
#include <hip/hip_runtime.h>
#include <math.h>

#define S 1024
#define C 128

#if __has_builtin(__builtin_amdgcn_exp2f)
__device__ __forceinline__ float EXP2(float x) { return __builtin_amdgcn_exp2f(x); }
#else
__device__ __forceinline__ float EXP2(float x) {
  float r; asm("v_exp_f32 %0, %1" : "=v"(r) : "v"(x)); return r;
}
#endif

__device__ __forceinline__ float wred_sum(float v) {
  #pragma unroll
  for (int off = 32; off; off >>= 1) v += __shfl_xor(v, off);
  return v;
}

// ---------------- prep: fused weight-transpose + GroupNorm ----------------
// blocks 0..63: GroupNorm (b,group); blocks 64..319: transpose 4 weight mats
// WT[k][512] = [Wq^T | Wk^T | Wv^T | Wo^T]
__global__ __launch_bounds__(256) void prep_kernel(const float* __restrict__ x,
                                                   const float* __restrict__ w,
                                                   const float* __restrict__ bias,
                                                   const float* __restrict__ Wq,
                                                   const float* __restrict__ Wk,
                                                   const float* __restrict__ Wv,
                                                   const float* __restrict__ Wo,
                                                   float* __restrict__ xn,
                                                   float* __restrict__ WT) {
  if (blockIdx.x >= 64) {
    int idx = (blockIdx.x - 64) * 256 + threadIdx.x;   // 65536 total
    int mat = idx >> 14, n = (idx >> 7) & 127, k = idx & 127;
    const float* W = mat == 0 ? Wq : (mat == 1 ? Wk : (mat == 2 ? Wv : Wo));
    WT[k * 512 + mat * 128 + n] = W[n * 128 + k];
    return;
  }
  const int b = blockIdx.x >> 5, g = blockIdx.x & 31;
  const float* xp = x + (size_t)(b * C + g * 4) * S;
  float* xnp = xn + (size_t)(b * C + g * 4) * S;
  float4 vals[4];
  float s = 0.f, ss = 0.f;
  #pragma unroll
  for (int i = 0; i < 4; ++i) {
    float4 v = ((const float4*)xp)[threadIdx.x + i * 256];
    vals[i] = v;
    s += (v.x + v.y) + (v.z + v.w);
    ss += v.x * v.x; ss += v.y * v.y; ss += v.z * v.z; ss += v.w * v.w;
  }
  s = wred_sum(s); ss = wred_sum(ss);
  __shared__ float red[8];
  const int lane = threadIdx.x & 63, wid = threadIdx.x >> 6;
  if (lane == 0) { red[wid] = s; red[4 + wid] = ss; }
  __syncthreads();
  float ts = (red[0] + red[1]) + (red[2] + red[3]);
  float tss = (red[4] + red[5]) + (red[6] + red[7]);
  float mean = ts * (1.f / 4096.f);
  float var = tss * (1.f / 4096.f) - mean * mean;
  float rstd = rsqrtf(var + 1e-5f);
  #pragma unroll
  for (int i = 0; i < 4; ++i) {
    float sc = w[g * 4 + i] * rstd;
    float sh = fmaf(-mean, sc, bias[g * 4 + i]);
    float4 v = vals[i];
    float4 o = make_float4(fmaf(v.x, sc, sh), fmaf(v.y, sc, sh),
                           fmaf(v.z, sc, sh), fmaf(v.w, sc, sh));
    ((float4*)xnp)[threadIdx.x + i * 256] = o;
  }
}

// ---------------- QKV GEMM: 64(M) x 32(N) tile, 256 thr, 4x2 microtile ----------------
__global__ __launch_bounds__(256) void gemm_qkv(const float* __restrict__ xn,
                                                const float* __restrict__ WT,
                                                const float* __restrict__ bq,
                                                const float* __restrict__ bk,
                                                const float* __restrict__ bv,
                                                float* __restrict__ qkv) {
  const int m0 = blockIdx.x * 64;
  const int nt = blockIdx.y;          // 0..11
  const int b = blockIdx.z;
  const int mat = nt >> 2, nloc = (nt & 3) * 32;
  const int col0 = mat * 128 + nloc;
  const float* biasp = (mat == 0 ? bq : (mat == 1 ? bk : bv)) + nloc;
  const float* Ab = xn + (size_t)b * C * S + m0;
  float* outp = qkv + ((size_t)mat * 2 + b) * (C * S) + (size_t)nloc * S + m0;

  __shared__ float As[32][64];
  __shared__ float Bs[32][32];
  const int tx = threadIdx.x & 15, ty = threadIdx.x >> 4;
  float acc[2][4] = {};

  for (int kt = 0; kt < 4; ++kt) {
    const int k0 = kt * 32;
    __syncthreads();
    #pragma unroll
    for (int i = threadIdx.x; i < 2048; i += 256) {
      int kk = i >> 6, mm = i & 63;
      As[kk][mm] = Ab[(size_t)(k0 + kk) * S + mm];
    }
    #pragma unroll
    for (int i = threadIdx.x; i < 1024; i += 256) {
      int kk = i >> 5, nn = i & 31;
      Bs[kk][nn] = WT[(k0 + kk) * 512 + col0 + nn];
    }
    __syncthreads();
    #pragma unroll
    for (int kk = 0; kk < 32; ++kk) {
      float4 a4 = *(const float4*)&As[kk][tx * 4];
      float2 b2 = *(const float2*)&Bs[kk][ty * 2];
      float av[4] = {a4.x, a4.y, a4.z, a4.w};
      float bv2[2] = {b2.x, b2.y};
      #pragma unroll
      for (int j = 0; j < 2; ++j)
        #pragma unroll
        for (int i = 0; i < 4; ++i)
          acc[j][i] = fmaf(bv2[j], av[i], acc[j][i]);
    }
  }
  #pragma unroll
  for (int j = 0; j < 2; ++j) {
    float bj = biasp[ty * 2 + j];
    float4 o = make_float4(acc[j][0] + bj, acc[j][1] + bj, acc[j][2] + bj, acc[j][3] + bj);
    *(float4*)&outp[(size_t)(ty * 2 + j) * S + tx * 4] = o;
  }
}

// ---------------- Attention: per (b,h): softmax(q_i * k[:]) @ v ----------------
// grid (8, 128, 2): 128 queries per block, 1 per thread; k,v staged in LDS.
__global__ __launch_bounds__(128) void attn_kernel(const float* __restrict__ qkv,
                                                   float* __restrict__ attnb) {
  const int h = blockIdx.y, b = blockIdx.z;
  const size_t base = ((size_t)b * C + h) * S;
  const float* qp = qkv + base;
  const float* kp = qkv + 2 * C * S + base;
  const float* vp = qkv + 4 * C * S + base;
  __shared__ float kl[S];
  __shared__ float vl[S];
  __shared__ float red[4];
  float kmax = -1e30f, kmin = 1e30f;
  #pragma unroll
  for (int i = threadIdx.x; i < 256; i += 128) {
    float4 k4 = ((const float4*)kp)[i];
    float4 v4 = ((const float4*)vp)[i];
    ((float4*)kl)[i] = k4;
    ((float4*)vl)[i] = v4;
    kmax = fmaxf(kmax, fmaxf(fmaxf(k4.x, k4.y), fmaxf(k4.z, k4.w)));
    kmin = fminf(kmin, fminf(fminf(k4.x, k4.y), fminf(k4.z, k4.w)));
  }
  #pragma unroll
  for (int off = 32; off; off >>= 1) {
    kmax = fmaxf(kmax, __shfl_xor(kmax, off));
    kmin = fminf(kmin, __shfl_xor(kmin, off));
  }
  const int lane = threadIdx.x & 63, wid = threadIdx.x >> 6;
  if (lane == 0) { red[wid] = kmax; red[2 + wid] = kmin; }
  __syncthreads();
  kmax = fmaxf(red[0], red[1]);
  kmin = fminf(red[2], red[3]);

  const int qi = blockIdx.x * 128 + threadIdx.x;
  const float LOG2E = 1.4426950408889634f;
  float qs = qp[qi] * LOG2E;                 // scale = 1 (HEAD_DIM=1)
  float nmb = -fmaxf(qs * kmax, qs * kmin);  // -max_j(qs*k_j), exact
  float den0 = 0.f, den1 = 0.f, den2 = 0.f, den3 = 0.f;
  float num0 = 0.f, num1 = 0.f, num2 = 0.f, num3 = 0.f;
  #pragma unroll 4
  for (int j8 = 0; j8 < S / 8; ++j8) {
    float4 ka = ((const float4*)kl)[2 * j8];
    float4 kb = ((const float4*)kl)[2 * j8 + 1];
    float4 va = ((const float4*)vl)[2 * j8];
    float4 vb = ((const float4*)vl)[2 * j8 + 1];
    float e0 = EXP2(fmaf(qs, ka.x, nmb));
    float e1 = EXP2(fmaf(qs, ka.y, nmb));
    float e2 = EXP2(fmaf(qs, ka.z, nmb));
    float e3 = EXP2(fmaf(qs, ka.w, nmb));
    float e4 = EXP2(fmaf(qs, kb.x, nmb));
    float e5 = EXP2(fmaf(qs, kb.y, nmb));
    float e6 = EXP2(fmaf(qs, kb.z, nmb));
    float e7 = EXP2(fmaf(qs, kb.w, nmb));
    den0 += e0; num0 = fmaf(e0, va.x, num0);
    den1 += e1; num1 = fmaf(e1, va.y, num1);
    den2 += e2; num2 = fmaf(e2, va.z, num2);
    den3 += e3; num3 = fmaf(e3, va.w, num3);
    den0 += e4; num0 = fmaf(e4, vb.x, num0);
    den1 += e5; num1 = fmaf(e5, vb.y, num1);
    den2 += e6; num2 = fmaf(e6, vb.z, num2);
    den3 += e7; num3 = fmaf(e7, vb.w, num3);
  }
  float num = (num0 + num1) + (num2 + num3);
  float den = (den0 + den1) + (den2 + den3);
  attnb[base + qi] = num / den;
}

// ---------------- Out proj + bias + residual: 64x32 tile ----------------
__global__ __launch_bounds__(256) void gemm_out(const float* __restrict__ attnb,
                                                const float* __restrict__ WT,
                                                const float* __restrict__ bo,
                                                const float* __restrict__ x,
                                                float* __restrict__ out) {
  const int m0 = blockIdx.x * 64;
  const int b = blockIdx.z;
  const int nloc = blockIdx.y * 32;
  const int col0 = 384 + nloc;
  const float* Ab = attnb + (size_t)b * C * S + m0;
  const float* biasp = bo + nloc;
  const float* resp = x + (size_t)b * C * S + (size_t)nloc * S + m0;
  float* outp = out + (size_t)b * C * S + (size_t)nloc * S + m0;

  __shared__ float As[32][64];
  __shared__ float Bs[32][32];
  const int tx = threadIdx.x & 15, ty = threadIdx.x >> 4;
  float acc[2][4] = {};

  for (int kt = 0; kt < 4; ++kt) {
    const int k0 = kt * 32;
    __syncthreads();
    #pragma unroll
    for (int i = threadIdx.x; i < 2048; i += 256) {
      int kk = i >> 6, mm = i & 63;
      As[kk][mm] = Ab[(size_t)(k0 + kk) * S + mm];
    }
    #pragma unroll
    for (int i = threadIdx.x; i < 1024; i += 256) {
      int kk = i >> 5, nn = i & 31;
      Bs[kk][nn] = WT[(k0 + kk) * 512 + col0 + nn];
    }
    __syncthreads();
    #pragma unroll
    for (int kk = 0; kk < 32; ++kk) {
      float4 a4 = *(const float4*)&As[kk][tx * 4];
      float2 b2 = *(const float2*)&Bs[kk][ty * 2];
      float av[4] = {a4.x, a4.y, a4.z, a4.w};
      float bv2[2] = {b2.x, b2.y};
      #pragma unroll
      for (int j = 0; j < 2; ++j)
        #pragma unroll
        for (int i = 0; i < 4; ++i)
          acc[j][i] = fmaf(bv2[j], av[i], acc[j][i]);
    }
  }
  #pragma unroll
  for (int j = 0; j < 2; ++j) {
    float bj = biasp[ty * 2 + j];
    const float* rrow = resp + (size_t)(ty * 2 + j) * S + tx * 4;
    float4 r = *(const float4*)rrow;
    float4 o = make_float4(acc[j][0] + bj + r.x, acc[j][1] + bj + r.y,
                           acc[j][2] + bj + r.z, acc[j][3] + bj + r.w);
    *(float4*)&outp[(size_t)(ty * 2 + j) * S + tx * 4] = o;
  }
}

extern "C" void kernel_launch(void* const* d_in, const int* in_sizes, int n_in,
                              void* d_out, int out_size, void* d_ws, size_t ws_size,
                              hipStream_t stream) {
  const float* x  = (const float*)d_in[0];
  const float* gw = (const float*)d_in[1];
  const float* gb = (const float*)d_in[2];
  const float* Wq = (const float*)d_in[3];
  const float* bq = (const float*)d_in[4];
  const float* Wk = (const float*)d_in[5];
  const float* bk = (const float*)d_in[6];
  const float* Wv = (const float*)d_in[7];
  const float* bv = (const float*)d_in[8];
  const float* Wo = (const float*)d_in[9];
  const float* bo = (const float*)d_in[10];
  float* out = (float*)d_out;

  float* ws = (float*)d_ws;
  float* xn  = ws;                       // 262144 floats (reused as attention output)
  float* qkv = ws + 262144;              // 786432 floats, layout [mat][b][C][S]
  float* WT  = ws + 262144 + 786432;     // 65536 floats: [k][512]

  hipLaunchKernelGGL(prep_kernel, dim3(320), dim3(256), 0, stream,
                     x, gw, gb, Wq, Wk, Wv, Wo, xn, WT);
  hipLaunchKernelGGL(gemm_qkv, dim3(16, 12, 2), dim3(256), 0, stream, xn, WT, bq, bk, bv, qkv);
  hipLaunchKernelGGL(attn_kernel, dim3(8, 128, 2), dim3(128), 0, stream, qkv, xn);
  hipLaunchKernelGGL(gemm_out, dim3(16, 4, 2), dim3(256), 0, stream, xn, WT, bo, x, out);
}

// Round 8
// 120.727 us; speedup vs baseline: 1.5140x; 1.1609x over previous
//
#include <hip/hip_runtime.h>
#include <math.h>

#define S 1024
#define C 128

#if __has_builtin(__builtin_amdgcn_exp2f)
__device__ __forceinline__ float EXP2(float x) { return __builtin_amdgcn_exp2f(x); }
#else
__device__ __forceinline__ float EXP2(float x) {
  float r; asm("v_exp_f32 %0, %1" : "=v"(r) : "v"(x)); return r;
}
#endif

typedef float v2f __attribute__((ext_vector_type(2)));

__device__ __forceinline__ float wred_sum(float v) {
  #pragma unroll
  for (int off = 32; off; off >>= 1) v += __shfl_xor(v, off);
  return v;
}

// ---------------- prep: fused weight-transpose + GroupNorm ----------------
// blocks 0..63: GroupNorm (b,group); blocks 64..319: transpose 4 weight mats
// WT[k][512] = [Wq^T | Wk^T | Wv^T | Wo^T]
__global__ __launch_bounds__(256) void prep_kernel(const float* __restrict__ x,
                                                   const float* __restrict__ w,
                                                   const float* __restrict__ bias,
                                                   const float* __restrict__ Wq,
                                                   const float* __restrict__ Wk,
                                                   const float* __restrict__ Wv,
                                                   const float* __restrict__ Wo,
                                                   float* __restrict__ xn,
                                                   float* __restrict__ WT) {
  if (blockIdx.x >= 64) {
    int idx = (blockIdx.x - 64) * 256 + threadIdx.x;   // 65536 total
    int mat = idx >> 14, n = (idx >> 7) & 127, k = idx & 127;
    const float* W = mat == 0 ? Wq : (mat == 1 ? Wk : (mat == 2 ? Wv : Wo));
    WT[k * 512 + mat * 128 + n] = W[n * 128 + k];
    return;
  }
  const int b = blockIdx.x >> 5, g = blockIdx.x & 31;
  const float* xp = x + (size_t)(b * C + g * 4) * S;
  float* xnp = xn + (size_t)(b * C + g * 4) * S;
  float4 vals[4];
  float s = 0.f, ss = 0.f;
  #pragma unroll
  for (int i = 0; i < 4; ++i) {
    float4 v = ((const float4*)xp)[threadIdx.x + i * 256];
    vals[i] = v;
    s += (v.x + v.y) + (v.z + v.w);
    ss += v.x * v.x; ss += v.y * v.y; ss += v.z * v.z; ss += v.w * v.w;
  }
  s = wred_sum(s); ss = wred_sum(ss);
  __shared__ float red[8];
  const int lane = threadIdx.x & 63, wid = threadIdx.x >> 6;
  if (lane == 0) { red[wid] = s; red[4 + wid] = ss; }
  __syncthreads();
  float ts = (red[0] + red[1]) + (red[2] + red[3]);
  float tss = (red[4] + red[5]) + (red[6] + red[7]);
  float mean = ts * (1.f / 4096.f);
  float var = tss * (1.f / 4096.f) - mean * mean;
  float rstd = rsqrtf(var + 1e-5f);
  #pragma unroll
  for (int i = 0; i < 4; ++i) {
    float sc = w[g * 4 + i] * rstd;
    float sh = fmaf(-mean, sc, bias[g * 4 + i]);
    float4 v = vals[i];
    float4 o = make_float4(fmaf(v.x, sc, sh), fmaf(v.y, sc, sh),
                           fmaf(v.z, sc, sh), fmaf(v.w, sc, sh));
    ((float4*)xnp)[threadIdx.x + i * 256] = o;
  }
}

// ---------------- QKV GEMM: 64(M) x 32(N) tile, full-K=128 single stage ----------------
__global__ __launch_bounds__(256) void gemm_qkv(const float* __restrict__ xn,
                                                const float* __restrict__ WT,
                                                const float* __restrict__ bq,
                                                const float* __restrict__ bk,
                                                const float* __restrict__ bv,
                                                float* __restrict__ qkv) {
  const int m0 = blockIdx.x * 64;
  const int nt = blockIdx.y;          // 0..11
  const int b = blockIdx.z;
  const int mat = nt >> 2, nloc = (nt & 3) * 32;
  const int col0 = mat * 128 + nloc;
  const float* biasp = (mat == 0 ? bq : (mat == 1 ? bk : bv)) + nloc;
  const float* Ab = xn + (size_t)b * C * S + m0;
  float* outp = qkv + ((size_t)mat * 2 + b) * (C * S) + (size_t)nloc * S + m0;

  __shared__ float As[128][64];   // 32 KB
  __shared__ float Bs[128][32];   // 16 KB
  const int tx = threadIdx.x & 15, ty = threadIdx.x >> 4;

  // stage all of A (128x64 = 2048 float4) and B (128x32 = 1024 float4)
  #pragma unroll
  for (int t = 0; t < 8; ++t) {
    int i = threadIdx.x + t * 256;
    int kk = i >> 4, m4 = (i & 15) * 4;
    *(float4*)&As[kk][m4] = *(const float4*)&Ab[(size_t)kk * S + m4];
  }
  #pragma unroll
  for (int t = 0; t < 4; ++t) {
    int i = threadIdx.x + t * 256;
    int kk = i >> 3, n4 = (i & 7) * 4;
    *(float4*)&Bs[kk][n4] = *(const float4*)&WT[kk * 512 + col0 + n4];
  }
  __syncthreads();

  float acc[2][4] = {};
  #pragma unroll 8
  for (int kk = 0; kk < 128; ++kk) {
    float4 a4 = *(const float4*)&As[kk][tx * 4];
    float2 b2 = *(const float2*)&Bs[kk][ty * 2];
    float av[4] = {a4.x, a4.y, a4.z, a4.w};
    float bv2[2] = {b2.x, b2.y};
    #pragma unroll
    for (int j = 0; j < 2; ++j)
      #pragma unroll
      for (int i = 0; i < 4; ++i)
        acc[j][i] = fmaf(bv2[j], av[i], acc[j][i]);
  }
  #pragma unroll
  for (int j = 0; j < 2; ++j) {
    float bj = biasp[ty * 2 + j];
    float4 o = make_float4(acc[j][0] + bj, acc[j][1] + bj, acc[j][2] + bj, acc[j][3] + bj);
    *(float4*)&outp[(size_t)(ty * 2 + j) * S + tx * 4] = o;
  }
}

// ---------------- Attention: per (b,h): softmax(q_i * k[:]) @ v ----------------
// grid (4, 128, 2) x 128 thr; 2 queries per thread; k,v staged in LDS (broadcast reads).
// v2f arithmetic relies on compiler fp-contract to form v_pk_fma_f32 (no inline asm:
// the hand-written pk_fma asm in the previous round produced absmax 81 — operand
// encoding not trustworthy, reverted to compiler-generated packed math).
__global__ __launch_bounds__(128) void attn_kernel(const float* __restrict__ qkv,
                                                   float* __restrict__ attnb) {
  const int h = blockIdx.y, b = blockIdx.z;
  const size_t base = ((size_t)b * C + h) * S;
  const float* qp = qkv + base;
  const float* kp = qkv + 2 * C * S + base;
  const float* vp = qkv + 4 * C * S + base;
  __shared__ float kl[S];
  __shared__ float vl[S];
  __shared__ float red[4];
  float kmax = -1e30f, kmin = 1e30f;
  #pragma unroll
  for (int i = threadIdx.x; i < 256; i += 128) {
    float4 k4 = ((const float4*)kp)[i];
    float4 v4 = ((const float4*)vp)[i];
    ((float4*)kl)[i] = k4;
    ((float4*)vl)[i] = v4;
    kmax = fmaxf(kmax, fmaxf(fmaxf(k4.x, k4.y), fmaxf(k4.z, k4.w)));
    kmin = fminf(kmin, fminf(fminf(k4.x, k4.y), fminf(k4.z, k4.w)));
  }
  #pragma unroll
  for (int off = 32; off; off >>= 1) {
    kmax = fmaxf(kmax, __shfl_xor(kmax, off));
    kmin = fminf(kmin, __shfl_xor(kmin, off));
  }
  const int lane = threadIdx.x & 63, wid = threadIdx.x >> 6;
  if (lane == 0) { red[wid] = kmax; red[2 + wid] = kmin; }
  __syncthreads();
  kmax = fmaxf(red[0], red[1]);
  kmin = fminf(red[2], red[3]);

  const float LOG2E = 1.4426950408889634f;
  const int qi = blockIdx.x * 256 + threadIdx.x;     // query A; query B = qi+128
  float qsA = qp[qi] * LOG2E;
  float qsB = qp[qi + 128] * LOG2E;
  float nmA = -fmaxf(qsA * kmax, qsA * kmin);        // -max_j(qsA*k_j), exact
  float nmB = -fmaxf(qsB * kmax, qsB * kmin);
  v2f qA = {qsA, qsA}, qB = {qsB, qsB};
  v2f nA = {nmA, nmA}, nB = {nmB, nmB};
  v2f dA0 = {0.f, 0.f}, dA1 = {0.f, 0.f}, uA0 = {0.f, 0.f}, uA1 = {0.f, 0.f};
  v2f dB0 = {0.f, 0.f}, dB1 = {0.f, 0.f}, uB0 = {0.f, 0.f}, uB1 = {0.f, 0.f};

  #pragma unroll 2
  for (int j8 = 0; j8 < S / 8; ++j8) {
    float4 ka = ((const float4*)kl)[2 * j8];
    float4 kb = ((const float4*)kl)[2 * j8 + 1];
    float4 va = ((const float4*)vl)[2 * j8];
    float4 vb = ((const float4*)vl)[2 * j8 + 1];
    v2f k01 = {ka.x, ka.y}, k23 = {ka.z, ka.w}, k45 = {kb.x, kb.y}, k67 = {kb.z, kb.w};
    v2f v01 = {va.x, va.y}, v23 = {va.z, va.w}, v45 = {vb.x, vb.y}, v67 = {vb.z, vb.w};
    v2f a, e;
    // query A
    a = qA * k01 + nA; e.x = EXP2(a.x); e.y = EXP2(a.y);
    dA0 += e; uA0 += e * v01;
    a = qA * k23 + nA; e.x = EXP2(a.x); e.y = EXP2(a.y);
    dA1 += e; uA1 += e * v23;
    a = qA * k45 + nA; e.x = EXP2(a.x); e.y = EXP2(a.y);
    dA0 += e; uA0 += e * v45;
    a = qA * k67 + nA; e.x = EXP2(a.x); e.y = EXP2(a.y);
    dA1 += e; uA1 += e * v67;
    // query B
    a = qB * k01 + nB; e.x = EXP2(a.x); e.y = EXP2(a.y);
    dB0 += e; uB0 += e * v01;
    a = qB * k23 + nB; e.x = EXP2(a.x); e.y = EXP2(a.y);
    dB1 += e; uB1 += e * v23;
    a = qB * k45 + nB; e.x = EXP2(a.x); e.y = EXP2(a.y);
    dB0 += e; uB0 += e * v45;
    a = qB * k67 + nB; e.x = EXP2(a.x); e.y = EXP2(a.y);
    dB1 += e; uB1 += e * v67;
  }
  float numA = (uA0.x + uA0.y) + (uA1.x + uA1.y);
  float denA = (dA0.x + dA0.y) + (dA1.x + dA1.y);
  float numB = (uB0.x + uB0.y) + (uB1.x + uB1.y);
  float denB = (dB0.x + dB0.y) + (dB1.x + dB1.y);
  attnb[base + qi] = numA / denA;
  attnb[base + qi + 128] = numB / denB;
}

// ---------------- Out proj + bias + residual: 32x32 tile, full-K=128 ----------------
__global__ __launch_bounds__(256) void gemm_out(const float* __restrict__ attnb,
                                                const float* __restrict__ WT,
                                                const float* __restrict__ bo,
                                                const float* __restrict__ x,
                                                float* __restrict__ out) {
  const int m0 = blockIdx.x * 32;
  const int b = blockIdx.z;
  const int nloc = blockIdx.y * 32;
  const int col0 = 384 + nloc;
  const float* Ab = attnb + (size_t)b * C * S + m0;
  float* outp = out + (size_t)b * C * S + (size_t)nloc * S + m0;
  const float* resp = x + (size_t)b * C * S + (size_t)nloc * S + m0;

  __shared__ float As[128][32];   // 16 KB
  __shared__ float Bs[128][32];   // 16 KB
  const int tx = threadIdx.x & 7, ty = threadIdx.x >> 3;   // tx->m4, ty->n

  #pragma unroll
  for (int t = 0; t < 4; ++t) {
    int i = threadIdx.x + t * 256;
    int kk = i >> 3, m4 = (i & 7) * 4;
    *(float4*)&As[kk][m4] = *(const float4*)&Ab[(size_t)kk * S + m4];
  }
  #pragma unroll
  for (int t = 0; t < 4; ++t) {
    int i = threadIdx.x + t * 256;
    int kk = i >> 3, n4 = (i & 7) * 4;
    *(float4*)&Bs[kk][n4] = *(const float4*)&WT[kk * 512 + col0 + n4];
  }
  __syncthreads();

  float acc[4] = {};
  #pragma unroll 8
  for (int kk = 0; kk < 128; ++kk) {
    float4 a4 = *(const float4*)&As[kk][tx * 4];
    float bb = Bs[kk][ty];
    acc[0] = fmaf(bb, a4.x, acc[0]);
    acc[1] = fmaf(bb, a4.y, acc[1]);
    acc[2] = fmaf(bb, a4.z, acc[2]);
    acc[3] = fmaf(bb, a4.w, acc[3]);
  }
  float bj = bo[nloc + ty];
  const float4 r = *(const float4*)&resp[(size_t)ty * S + tx * 4];
  float4 o = make_float4(acc[0] + bj + r.x, acc[1] + bj + r.y,
                         acc[2] + bj + r.z, acc[3] + bj + r.w);
  *(float4*)&outp[(size_t)ty * S + tx * 4] = o;
}

extern "C" void kernel_launch(void* const* d_in, const int* in_sizes, int n_in,
                              void* d_out, int out_size, void* d_ws, size_t ws_size,
                              hipStream_t stream) {
  const float* x  = (const float*)d_in[0];
  const float* gw = (const float*)d_in[1];
  const float* gb = (const float*)d_in[2];
  const float* Wq = (const float*)d_in[3];
  const float* bq = (const float*)d_in[4];
  const float* Wk = (const float*)d_in[5];
  const float* bk = (const float*)d_in[6];
  const float* Wv = (const float*)d_in[7];
  const float* bv = (const float*)d_in[8];
  const float* Wo = (const float*)d_in[9];
  const float* bo = (const float*)d_in[10];
  float* out = (float*)d_out;

  float* ws = (float*)d_ws;
  float* xn  = ws;                       // 262144 floats (reused as attention output)
  float* qkv = ws + 262144;              // 786432 floats, layout [mat][b][C][S]
  float* WT  = ws + 262144 + 786432;     // 65536 floats: [k][512]

  hipLaunchKernelGGL(prep_kernel, dim3(320), dim3(256), 0, stream,
                     x, gw, gb, Wq, Wk, Wv, Wo, xn, WT);
  hipLaunchKernelGGL(gemm_qkv, dim3(16, 12, 2), dim3(256), 0, stream, xn, WT, bq, bk, bv, qkv);
  hipLaunchKernelGGL(attn_kernel, dim3(4, 128, 2), dim3(128), 0, stream, qkv, xn);
  hipLaunchKernelGGL(gemm_out, dim3(32, 4, 2), dim3(256), 0, stream, xn, WT, bo, x, out);
}

// Round 10
// 120.651 us; speedup vs baseline: 1.5149x; 1.0006x over previous
//
#include <hip/hip_runtime.h>
#include <math.h>

#define S 1024
#define C 128

#if __has_builtin(__builtin_amdgcn_exp2f)
__device__ __forceinline__ float EXP2(float x) { return __builtin_amdgcn_exp2f(x); }
#else
__device__ __forceinline__ float EXP2(float x) {
  float r; asm("v_exp_f32 %0, %1" : "=v"(r) : "v"(x)); return r;
}
#endif

typedef float v2f __attribute__((ext_vector_type(2)));

__device__ __forceinline__ float wred_sum(float v) {
  #pragma unroll
  for (int off = 32; off; off >>= 1) v += __shfl_xor(v, off);
  return v;
}

// ---------------- prep: GN stats + weight transpose ----------------
// blocks 0..63: per-(b,group) mean/rstd only (no xn materialization);
// blocks 64..319: transpose 4 weight mats into WT[k][512] = [Wq^T|Wk^T|Wv^T|Wo^T]
__global__ __launch_bounds__(256) void prep_kernel(const float* __restrict__ x,
                                                   const float* __restrict__ Wq,
                                                   const float* __restrict__ Wk,
                                                   const float* __restrict__ Wv,
                                                   const float* __restrict__ Wo,
                                                   float2* __restrict__ stats,
                                                   float* __restrict__ WT) {
  if (blockIdx.x >= 64) {
    int idx = (blockIdx.x - 64) * 256 + threadIdx.x;   // 65536 total
    int mat = idx >> 14, n = (idx >> 7) & 127, k = idx & 127;
    const float* W = mat == 0 ? Wq : (mat == 1 ? Wk : (mat == 2 ? Wv : Wo));
    WT[k * 512 + mat * 128 + n] = W[n * 128 + k];
    return;
  }
  const int b = blockIdx.x >> 5, g = blockIdx.x & 31;
  const float* xp = x + (size_t)(b * C + g * 4) * S;
  float s = 0.f, ss = 0.f;
  #pragma unroll
  for (int i = 0; i < 4; ++i) {
    float4 v = ((const float4*)xp)[threadIdx.x + i * 256];
    s += (v.x + v.y) + (v.z + v.w);
    ss += v.x * v.x; ss += v.y * v.y; ss += v.z * v.z; ss += v.w * v.w;
  }
  s = wred_sum(s); ss = wred_sum(ss);
  __shared__ float red[8];
  const int lane = threadIdx.x & 63, wid = threadIdx.x >> 6;
  if (lane == 0) { red[wid] = s; red[4 + wid] = ss; }
  __syncthreads();
  if (threadIdx.x == 0) {
    float ts = (red[0] + red[1]) + (red[2] + red[3]);
    float tss = (red[4] + red[5]) + (red[6] + red[7]);
    float mean = ts * (1.f / 4096.f);
    float var = tss * (1.f / 4096.f) - mean * mean;
    stats[b * 32 + g] = make_float2(mean, rsqrtf(var + 1e-5f));
  }
}

// ---------------- QKV GEMM with fused GroupNorm on A-staging ----------------
// out[n][m] = sum_k (x[b][k][m]*sc[k]+sh[k]) * W[n][k] + bias[n]
// 64(M) x 32(N) tile, full-K=128 single stage.
__global__ __launch_bounds__(256) void gemm_qkv(const float* __restrict__ x,
                                                const float2* __restrict__ stats,
                                                const float* __restrict__ gw,
                                                const float* __restrict__ gb,
                                                const float* __restrict__ WT,
                                                const float* __restrict__ bq,
                                                const float* __restrict__ bk,
                                                const float* __restrict__ bv,
                                                float* __restrict__ qkv) {
  const int m0 = blockIdx.x * 64;
  const int nt = blockIdx.y;          // 0..11
  const int b = blockIdx.z;
  const int mat = nt >> 2, nloc = (nt & 3) * 32;
  const int col0 = mat * 128 + nloc;
  const float* biasp = (mat == 0 ? bq : (mat == 1 ? bk : bv)) + nloc;
  const float* Ab = x + (size_t)b * C * S + m0;
  float* outp = qkv + ((size_t)mat * 2 + b) * (C * S) + (size_t)nloc * S + m0;

  __shared__ float As[128][64];   // 32 KB
  __shared__ float Bs[128][32];   // 16 KB
  __shared__ float scs[128], shs[128];
  const int tx = threadIdx.x & 15, ty = threadIdx.x >> 4;

  // per-channel scale/shift from group stats
  if (threadIdx.x < 128) {
    int ch = threadIdx.x;
    float2 st = stats[b * 32 + (ch >> 2)];    // mean, rstd
    float sc = gw[ch] * st.y;
    scs[ch] = sc;
    shs[ch] = fmaf(-st.x, sc, gb[ch]);
  }
  __syncthreads();

  // stage A (128x64) with GN applied, and B (128x32)
  #pragma unroll
  for (int t = 0; t < 8; ++t) {
    int i = threadIdx.x + t * 256;
    int kk = i >> 4, m4 = (i & 15) * 4;
    float4 xv = *(const float4*)&Ab[(size_t)kk * S + m4];
    float sc = scs[kk], sh = shs[kk];
    float4 o = make_float4(fmaf(xv.x, sc, sh), fmaf(xv.y, sc, sh),
                           fmaf(xv.z, sc, sh), fmaf(xv.w, sc, sh));
    *(float4*)&As[kk][m4] = o;
  }
  #pragma unroll
  for (int t = 0; t < 4; ++t) {
    int i = threadIdx.x + t * 256;
    int kk = i >> 3, n4 = (i & 7) * 4;
    *(float4*)&Bs[kk][n4] = *(const float4*)&WT[kk * 512 + col0 + n4];
  }
  __syncthreads();

  float acc[2][4] = {};
  #pragma unroll 8
  for (int kk = 0; kk < 128; ++kk) {
    float4 a4 = *(const float4*)&As[kk][tx * 4];
    float2 b2 = *(const float2*)&Bs[kk][ty * 2];
    float av[4] = {a4.x, a4.y, a4.z, a4.w};
    float bv2[2] = {b2.x, b2.y};
    #pragma unroll
    for (int j = 0; j < 2; ++j)
      #pragma unroll
      for (int i = 0; i < 4; ++i)
        acc[j][i] = fmaf(bv2[j], av[i], acc[j][i]);
  }
  #pragma unroll
  for (int j = 0; j < 2; ++j) {
    float bj = biasp[ty * 2 + j];
    float4 o = make_float4(acc[j][0] + bj, acc[j][1] + bj, acc[j][2] + bj, acc[j][3] + bj);
    *(float4*)&outp[(size_t)(ty * 2 + j) * S + tx * 4] = o;
  }
}

// ---------------- Attention: per (b,h): softmax(q_i * k[:]) @ v ----------------
// grid (4, 128, 2) x 128 thr; 2 queries per thread; k,v in LDS (broadcast reads).
// No max-subtraction: softmax is shift-invariant and |qs*k| << 126, so exp2
// cannot overflow; dropped terms are negligible by construction.
__global__ __launch_bounds__(128) void attn_kernel(const float* __restrict__ qkv,
                                                   float* __restrict__ attnb) {
  const int h = blockIdx.y, b = blockIdx.z;
  const size_t base = ((size_t)b * C + h) * S;
  const float* qp = qkv + base;
  const float* kp = qkv + 2 * C * S + base;
  const float* vp = qkv + 4 * C * S + base;
  __shared__ float kl[S];
  __shared__ float vl[S];
  #pragma unroll
  for (int i = threadIdx.x; i < 256; i += 128) {
    ((float4*)kl)[i] = ((const float4*)kp)[i];
    ((float4*)vl)[i] = ((const float4*)vp)[i];
  }
  __syncthreads();

  const float LOG2E = 1.4426950408889634f;
  const int qi = blockIdx.x * 256 + threadIdx.x;     // query A; query B = qi+128
  float qsA = qp[qi] * LOG2E;
  float qsB = qp[qi + 128] * LOG2E;
  v2f qA = {qsA, qsA}, qB = {qsB, qsB};
  v2f dA0 = {0.f, 0.f}, dA1 = {0.f, 0.f}, uA0 = {0.f, 0.f}, uA1 = {0.f, 0.f};
  v2f dB0 = {0.f, 0.f}, dB1 = {0.f, 0.f}, uB0 = {0.f, 0.f}, uB1 = {0.f, 0.f};

  #pragma unroll 2
  for (int j8 = 0; j8 < S / 8; ++j8) {
    float4 ka = ((const float4*)kl)[2 * j8];
    float4 kb = ((const float4*)kl)[2 * j8 + 1];
    float4 va = ((const float4*)vl)[2 * j8];
    float4 vb = ((const float4*)vl)[2 * j8 + 1];
    v2f k01 = {ka.x, ka.y}, k23 = {ka.z, ka.w}, k45 = {kb.x, kb.y}, k67 = {kb.z, kb.w};
    v2f v01 = {va.x, va.y}, v23 = {va.z, va.w}, v45 = {vb.x, vb.y}, v67 = {vb.z, vb.w};
    v2f a, e;
    // query A
    a = qA * k01; e.x = EXP2(a.x); e.y = EXP2(a.y);
    dA0 += e; uA0 += e * v01;
    a = qA * k23; e.x = EXP2(a.x); e.y = EXP2(a.y);
    dA1 += e; uA1 += e * v23;
    a = qA * k45; e.x = EXP2(a.x); e.y = EXP2(a.y);
    dA0 += e; uA0 += e * v45;
    a = qA * k67; e.x = EXP2(a.x); e.y = EXP2(a.y);
    dA1 += e; uA1 += e * v67;
    // query B
    a = qB * k01; e.x = EXP2(a.x); e.y = EXP2(a.y);
    dB0 += e; uB0 += e * v01;
    a = qB * k23; e.x = EXP2(a.x); e.y = EXP2(a.y);
    dB1 += e; uB1 += e * v23;
    a = qB * k45; e.x = EXP2(a.x); e.y = EXP2(a.y);
    dB0 += e; uB0 += e * v45;
    a = qB * k67; e.x = EXP2(a.x); e.y = EXP2(a.y);
    dB1 += e; uB1 += e * v67;
  }
  float numA = (uA0.x + uA0.y) + (uA1.x + uA1.y);
  float denA = (dA0.x + dA0.y) + (dA1.x + dA1.y);
  float numB = (uB0.x + uB0.y) + (uB1.x + uB1.y);
  float denB = (dB0.x + dB0.y) + (dB1.x + dB1.y);
  attnb[base + qi] = numA / denA;
  attnb[base + qi + 128] = numB / denB;
}

// ---------------- Out proj + bias + residual: 32x32 tile, full-K=128 ----------------
__global__ __launch_bounds__(256) void gemm_out(const float* __restrict__ attnb,
                                                const float* __restrict__ WT,
                                                const float* __restrict__ bo,
                                                const float* __restrict__ x,
                                                float* __restrict__ out) {
  const int m0 = blockIdx.x * 32;
  const int b = blockIdx.z;
  const int nloc = blockIdx.y * 32;
  const int col0 = 384 + nloc;
  const float* Ab = attnb + (size_t)b * C * S + m0;
  float* outp = out + (size_t)b * C * S + (size_t)nloc * S + m0;
  const float* resp = x + (size_t)b * C * S + (size_t)nloc * S + m0;

  __shared__ float As[128][32];   // 16 KB
  __shared__ float Bs[128][32];   // 16 KB
  const int tx = threadIdx.x & 7, ty = threadIdx.x >> 3;   // tx->m4, ty->n

  #pragma unroll
  for (int t = 0; t < 4; ++t) {
    int i = threadIdx.x + t * 256;
    int kk = i >> 3, m4 = (i & 7) * 4;
    *(float4*)&As[kk][m4] = *(const float4*)&Ab[(size_t)kk * S + m4];
  }
  #pragma unroll
  for (int t = 0; t < 4; ++t) {
    int i = threadIdx.x + t * 256;
    int kk = i >> 3, n4 = (i & 7) * 4;
    *(float4*)&Bs[kk][n4] = *(const float4*)&WT[kk * 512 + col0 + n4];
  }
  __syncthreads();

  float acc[4] = {};
  #pragma unroll 8
  for (int kk = 0; kk < 128; ++kk) {
    float4 a4 = *(const float4*)&As[kk][tx * 4];
    float bb = Bs[kk][ty];
    acc[0] = fmaf(bb, a4.x, acc[0]);
    acc[1] = fmaf(bb, a4.y, acc[1]);
    acc[2] = fmaf(bb, a4.z, acc[2]);
    acc[3] = fmaf(bb, a4.w, acc[3]);
  }
  float bj = bo[nloc + ty];
  const float4 r = *(const float4*)&resp[(size_t)ty * S + tx * 4];
  float4 o = make_float4(acc[0] + bj + r.x, acc[1] + bj + r.y,
                         acc[2] + bj + r.z, acc[3] + bj + r.w);
  *(float4*)&outp[(size_t)ty * S + tx * 4] = o;
}

extern "C" void kernel_launch(void* const* d_in, const int* in_sizes, int n_in,
                              void* d_out, int out_size, void* d_ws, size_t ws_size,
                              hipStream_t stream) {
  const float* x  = (const float*)d_in[0];
  const float* gw = (const float*)d_in[1];
  const float* gb = (const float*)d_in[2];
  const float* Wq = (const float*)d_in[3];
  const float* bq = (const float*)d_in[4];
  const float* Wk = (const float*)d_in[5];
  const float* bk = (const float*)d_in[6];
  const float* Wv = (const float*)d_in[7];
  const float* bv = (const float*)d_in[8];
  const float* Wo = (const float*)d_in[9];
  const float* bo = (const float*)d_in[10];
  float* out = (float*)d_out;

  float* ws = (float*)d_ws;
  float* attnb = ws;                         // 262144 floats (attention output)
  float* qkv   = ws + 262144;                // 786432 floats, layout [mat][b][C][S]
  float* WT    = ws + 262144 + 786432;       // 65536 floats: [k][512]
  float2* stats = (float2*)(ws + 262144 + 786432 + 65536);  // 64 float2

  hipLaunchKernelGGL(prep_kernel, dim3(320), dim3(256), 0, stream,
                     x, Wq, Wk, Wv, Wo, stats, WT);
  hipLaunchKernelGGL(gemm_qkv, dim3(16, 12, 2), dim3(256), 0, stream,
                     x, stats, gw, gb, WT, bq, bk, bv, qkv);
  hipLaunchKernelGGL(attn_kernel, dim3(4, 128, 2), dim3(128), 0, stream, qkv, attnb);
  hipLaunchKernelGGL(gemm_out, dim3(32, 4, 2), dim3(256), 0, stream, attnb, WT, bo, x, out);
}

// Round 12
// 119.275 us; speedup vs baseline: 1.5324x; 1.0115x over previous
//
#include <hip/hip_runtime.h>
#include <math.h>

#define S 1024
#define C 128

#if __has_builtin(__builtin_amdgcn_exp2f)
__device__ __forceinline__ float EXP2(float x) { return __builtin_amdgcn_exp2f(x); }
#else
__device__ __forceinline__ float EXP2(float x) {
  float r; asm("v_exp_f32 %0, %1" : "=v"(r) : "v"(x)); return r;
}
#endif

typedef float v2f __attribute__((ext_vector_type(2)));

__device__ __forceinline__ float wred_sum(float v) {
  #pragma unroll
  for (int off = 32; off; off >>= 1) v += __shfl_xor(v, off);
  return v;
}

// ---------------- prep: GN stats + weight transpose ----------------
// blocks 0..63: per-(b,group) mean/rstd; blocks 64..319: transpose 4 weight
// mats into WT[k][512] = [Wq^T|Wk^T|Wv^T|Wo^T]
__global__ __launch_bounds__(256) void prep_kernel(const float* __restrict__ x,
                                                   const float* __restrict__ Wq,
                                                   const float* __restrict__ Wk,
                                                   const float* __restrict__ Wv,
                                                   const float* __restrict__ Wo,
                                                   float2* __restrict__ stats,
                                                   float* __restrict__ WT) {
  if (blockIdx.x >= 64) {
    int idx = (blockIdx.x - 64) * 256 + threadIdx.x;   // 65536 total
    int mat = idx >> 14, n = (idx >> 7) & 127, k = idx & 127;
    const float* W = mat == 0 ? Wq : (mat == 1 ? Wk : (mat == 2 ? Wv : Wo));
    WT[k * 512 + mat * 128 + n] = W[n * 128 + k];
    return;
  }
  const int b = blockIdx.x >> 5, g = blockIdx.x & 31;
  const float* xp = x + (size_t)(b * C + g * 4) * S;
  float s = 0.f, ss = 0.f;
  #pragma unroll
  for (int i = 0; i < 4; ++i) {
    float4 v = ((const float4*)xp)[threadIdx.x + i * 256];
    s += (v.x + v.y) + (v.z + v.w);
    ss += v.x * v.x; ss += v.y * v.y; ss += v.z * v.z; ss += v.w * v.w;
  }
  s = wred_sum(s); ss = wred_sum(ss);
  __shared__ float red[8];
  const int lane = threadIdx.x & 63, wid = threadIdx.x >> 6;
  if (lane == 0) { red[wid] = s; red[4 + wid] = ss; }
  __syncthreads();
  if (threadIdx.x == 0) {
    float ts = (red[0] + red[1]) + (red[2] + red[3]);
    float tss = (red[4] + red[5]) + (red[6] + red[7]);
    float mean = ts * (1.f / 4096.f);
    float var = tss * (1.f / 4096.f) - mean * mean;
    stats[b * 32 + g] = make_float2(mean, rsqrtf(var + 1e-5f));
  }
}

// ---------------- QKV GEMM with fused GroupNorm on A-staging ----------------
// 32(M) x 32(N) tile, 128 threads, full-K=128 single stage; 768 blocks for
// cross-block staging/compute overlap (33 KB LDS -> 4 blocks/CU possible).
__global__ __launch_bounds__(128) void gemm_qkv(const float* __restrict__ x,
                                                const float2* __restrict__ stats,
                                                const float* __restrict__ gw,
                                                const float* __restrict__ gb,
                                                const float* __restrict__ WT,
                                                const float* __restrict__ bq,
                                                const float* __restrict__ bk,
                                                const float* __restrict__ bv,
                                                float* __restrict__ qkv) {
  const int m0 = blockIdx.x * 32;
  const int nt = blockIdx.y;          // 0..11
  const int b = blockIdx.z;
  const int mat = nt >> 2, nloc = (nt & 3) * 32;
  const int col0 = mat * 128 + nloc;
  const float* biasp = (mat == 0 ? bq : (mat == 1 ? bk : bv)) + nloc;
  const float* Ab = x + (size_t)b * C * S + m0;
  float* outp = qkv + ((size_t)mat * 2 + b) * (C * S) + (size_t)nloc * S + m0;

  __shared__ float As[128][32];   // 16 KB
  __shared__ float Bs[128][32];   // 16 KB
  __shared__ float scs[128], shs[128];
  const int tx = threadIdx.x & 7, ty = threadIdx.x >> 3;   // tx->m4, ty->n2

  // per-channel scale/shift from group stats (128 threads, one channel each)
  {
    int ch = threadIdx.x;
    float2 st = stats[b * 32 + (ch >> 2)];    // mean, rstd
    float sc = gw[ch] * st.y;
    scs[ch] = sc;
    shs[ch] = fmaf(-st.x, sc, gb[ch]);
  }
  __syncthreads();

  // stage A (128k x 32m) with GN applied, and B (128k x 32n)
  #pragma unroll
  for (int t = 0; t < 8; ++t) {
    int i = threadIdx.x + t * 128;
    int kk = i >> 3, m4 = (i & 7) * 4;
    float4 xv = *(const float4*)&Ab[(size_t)kk * S + m4];
    float sc = scs[kk], sh = shs[kk];
    float4 o = make_float4(fmaf(xv.x, sc, sh), fmaf(xv.y, sc, sh),
                           fmaf(xv.z, sc, sh), fmaf(xv.w, sc, sh));
    *(float4*)&As[kk][m4] = o;
  }
  #pragma unroll
  for (int t = 0; t < 8; ++t) {
    int i = threadIdx.x + t * 128;
    int kk = i >> 3, n4 = (i & 7) * 4;
    *(float4*)&Bs[kk][n4] = *(const float4*)&WT[kk * 512 + col0 + n4];
  }
  __syncthreads();

  float acc[2][4] = {};
  #pragma unroll 8
  for (int kk = 0; kk < 128; ++kk) {
    float4 a4 = *(const float4*)&As[kk][tx * 4];
    float2 b2 = *(const float2*)&Bs[kk][ty * 2];
    float av[4] = {a4.x, a4.y, a4.z, a4.w};
    float bv2[2] = {b2.x, b2.y};
    #pragma unroll
    for (int j = 0; j < 2; ++j)
      #pragma unroll
      for (int i = 0; i < 4; ++i)
        acc[j][i] = fmaf(bv2[j], av[i], acc[j][i]);
  }
  #pragma unroll
  for (int j = 0; j < 2; ++j) {
    float bj = biasp[ty * 2 + j];
    float4 o = make_float4(acc[j][0] + bj, acc[j][1] + bj, acc[j][2] + bj, acc[j][3] + bj);
    *(float4*)&outp[(size_t)(ty * 2 + j) * S + tx * 4] = o;
  }
}

// ---------------- Attention: per (b,h): softmax(q_i * k[:]) @ v ----------------
// grid (8, 128, 2) x 128 thr; 1 query/thread -> 2048 blocks = 4 waves/SIMD
// (fills exp->accumulate dependency bubbles; per-score cost identical to
// 2q/thread, occupancy doubled). No max-subtraction (shift-invariant,
// |qs*k| << 126 so exp2 cannot overflow).
__global__ __launch_bounds__(128) void attn_kernel(const float* __restrict__ qkv,
                                                   float* __restrict__ attnb) {
  const int h = blockIdx.y, b = blockIdx.z;
  const size_t base = ((size_t)b * C + h) * S;
  const float* qp = qkv + base;
  const float* kp = qkv + 2 * C * S + base;
  const float* vp = qkv + 4 * C * S + base;
  __shared__ float kl[S];
  __shared__ float vl[S];
  #pragma unroll
  for (int i = threadIdx.x; i < 256; i += 128) {
    ((float4*)kl)[i] = ((const float4*)kp)[i];
    ((float4*)vl)[i] = ((const float4*)vp)[i];
  }
  __syncthreads();

  const float LOG2E = 1.4426950408889634f;
  const int qi = blockIdx.x * 128 + threadIdx.x;
  float qs = qp[qi] * LOG2E;
  v2f qA = {qs, qs};
  v2f d0 = {0.f, 0.f}, d1 = {0.f, 0.f}, u0 = {0.f, 0.f}, u1 = {0.f, 0.f};

  #pragma unroll 4
  for (int j8 = 0; j8 < S / 8; ++j8) {
    float4 ka = ((const float4*)kl)[2 * j8];
    float4 kb = ((const float4*)kl)[2 * j8 + 1];
    float4 va = ((const float4*)vl)[2 * j8];
    float4 vb = ((const float4*)vl)[2 * j8 + 1];
    v2f k01 = {ka.x, ka.y}, k23 = {ka.z, ka.w}, k45 = {kb.x, kb.y}, k67 = {kb.z, kb.w};
    v2f v01 = {va.x, va.y}, v23 = {va.z, va.w}, v45 = {vb.x, vb.y}, v67 = {vb.z, vb.w};
    v2f a, e;
    a = qA * k01; e.x = EXP2(a.x); e.y = EXP2(a.y);
    d0 += e; u0 += e * v01;
    a = qA * k23; e.x = EXP2(a.x); e.y = EXP2(a.y);
    d1 += e; u1 += e * v23;
    a = qA * k45; e.x = EXP2(a.x); e.y = EXP2(a.y);
    d0 += e; u0 += e * v45;
    a = qA * k67; e.x = EXP2(a.x); e.y = EXP2(a.y);
    d1 += e; u1 += e * v67;
  }
  float num = (u0.x + u0.y) + (u1.x + u1.y);
  float den = (d0.x + d0.y) + (d1.x + d1.y);
  attnb[base + qi] = num / den;
}

// ---------------- Out proj + bias + residual: 32x32 tile, full-K=128 ----------------
__global__ __launch_bounds__(256) void gemm_out(const float* __restrict__ attnb,
                                                const float* __restrict__ WT,
                                                const float* __restrict__ bo,
                                                const float* __restrict__ x,
                                                float* __restrict__ out) {
  const int m0 = blockIdx.x * 32;
  const int b = blockIdx.z;
  const int nloc = blockIdx.y * 32;
  const int col0 = 384 + nloc;
  const float* Ab = attnb + (size_t)b * C * S + m0;
  float* outp = out + (size_t)b * C * S + (size_t)nloc * S + m0;
  const float* resp = x + (size_t)b * C * S + (size_t)nloc * S + m0;

  __shared__ float As[128][32];   // 16 KB
  __shared__ float Bs[128][32];   // 16 KB
  const int tx = threadIdx.x & 7, ty = threadIdx.x >> 3;   // tx->m4, ty->n

  #pragma unroll
  for (int t = 0; t < 4; ++t) {
    int i = threadIdx.x + t * 256;
    int kk = i >> 3, m4 = (i & 7) * 4;
    *(float4*)&As[kk][m4] = *(const float4*)&Ab[(size_t)kk * S + m4];
  }
  #pragma unroll
  for (int t = 0; t < 4; ++t) {
    int i = threadIdx.x + t * 256;
    int kk = i >> 3, n4 = (i & 7) * 4;
    *(float4*)&Bs[kk][n4] = *(const float4*)&WT[kk * 512 + col0 + n4];
  }
  __syncthreads();

  float acc[4] = {};
  #pragma unroll 8
  for (int kk = 0; kk < 128; ++kk) {
    float4 a4 = *(const float4*)&As[kk][tx * 4];
    float bb = Bs[kk][ty];
    acc[0] = fmaf(bb, a4.x, acc[0]);
    acc[1] = fmaf(bb, a4.y, acc[1]);
    acc[2] = fmaf(bb, a4.z, acc[2]);
    acc[3] = fmaf(bb, a4.w, acc[3]);
  }
  float bj = bo[nloc + ty];
  const float4 r = *(const float4*)&resp[(size_t)ty * S + tx * 4];
  float4 o = make_float4(acc[0] + bj + r.x, acc[1] + bj + r.y,
                         acc[2] + bj + r.z, acc[3] + bj + r.w);
  *(float4*)&outp[(size_t)ty * S + tx * 4] = o;
}

extern "C" void kernel_launch(void* const* d_in, const int* in_sizes, int n_in,
                              void* d_out, int out_size, void* d_ws, size_t ws_size,
                              hipStream_t stream) {
  const float* x  = (const float*)d_in[0];
  const float* gw = (const float*)d_in[1];
  const float* gb = (const float*)d_in[2];
  const float* Wq = (const float*)d_in[3];
  const float* bq = (const float*)d_in[4];
  const float* Wk = (const float*)d_in[5];
  const float* bk = (const float*)d_in[6];
  const float* Wv = (const float*)d_in[7];
  const float* bv = (const float*)d_in[8];
  const float* Wo = (const float*)d_in[9];
  const float* bo = (const float*)d_in[10];
  float* out = (float*)d_out;

  float* ws = (float*)d_ws;
  float* attnb = ws;                         // 262144 floats (attention output)
  float* qkv   = ws + 262144;                // 786432 floats, layout [mat][b][C][S]
  float* WT    = ws + 262144 + 786432;       // 65536 floats: [k][512]
  float2* stats = (float2*)(ws + 262144 + 786432 + 65536);  // 64 float2

  hipLaunchKernelGGL(prep_kernel, dim3(320), dim3(256), 0, stream,
                     x, Wq, Wk, Wv, Wo, stats, WT);
  hipLaunchKernelGGL(gemm_qkv, dim3(32, 12, 2), dim3(128), 0, stream,
                     x, stats, gw, gb, WT, bq, bk, bv, qkv);
  hipLaunchKernelGGL(attn_kernel, dim3(8, 128, 2), dim3(128), 0, stream, qkv, attnb);
  hipLaunchKernelGGL(gemm_out, dim3(32, 4, 2), dim3(256), 0, stream, attnb, WT, bo, x, out);
}